// Round 1
// baseline (154.204 us; speedup 1.0000x reference)
//
#include <hip/hip_runtime.h>

#define NCH 32          // channels
#define GROUPS 8        // float4 groups per row (32 / 4)
#define KVOL 27         // 3^3 kernel offsets
#define LG 100          // grid side
#define LP 102          // padded side (1-cell zero ring)
#define RGN 5           // region side per block
#define NRGN 20         // LG / RGN
#define NREGIONS (NRGN * NRGN * NRGN)   // 8000
#define BSIDE 7         // RGN + 2
#define BVOL 343        // brick cells
#define CELLS 125       // RGN^3
#define FSTRIDE 9       // float4 stride for feat/kw rows (odd -> bank spread)
#define FEAT_SLOTS 168  // slot 0 = zero dummy; capacity 167 real slots
#define FEAT_CAP (FEAT_SLOTS - 1)
#define LSTR 28         // ushort tap-list stride (mult of 4 -> 56B, b64-aligned)

// ---- Kernel 1: padded dense presence map: dense[flatp] = row+1 --------------
__global__ void build_dense(const int* __restrict__ coords,
                            int* __restrict__ dense, int N) {
    int i = blockIdx.x * blockDim.x + threadIdx.x;
    if (i >= N) return;
    int x = coords[3 * i + 0];
    int y = coords[3 * i + 1];
    int z = coords[3 * i + 2];
    dense[((size_t)(x + 1) * LP + (y + 1)) * LP + (z + 1)] = i + 1;
}

// ---- Kernel 2: region gather with LDS feature staging -----------------------
// Per block: load 7^3 presence brick, assign compact slots to ALL occupied
// brick cells, stage their feature rows into LDS once (coalesced), build
// padded per-cell tap lists (slot<<5|k as ushort), then run the inner loop
// entirely out of LDS (feat + kw reads, stride-9 rows -> bank spread).
__global__ __launch_bounds__(256) void gather_conv_region(
        const int* __restrict__ dense,
        const float4* __restrict__ in_feats4,
        const float4* __restrict__ kernel4,
        float4* __restrict__ out4) {
    __shared__ float4 feat[FEAT_SLOTS * FSTRIDE];   // 24192 B
    __shared__ float4 kw[(KVOL + 1) * FSTRIDE];     //  4032 B (row 27 = zeros)
    __shared__ int bs[BVOL];                        // presence -> slot map
    __shared__ int slotrow[BVOL + 1];               // slot -> global feat row
    __shared__ int cellq[CELLS];                    // interior occupied queue
    __shared__ __align__(16) unsigned short list[CELLS * LSTR]; // 7000 B
    __shared__ int nslots, nint;

    int tid = threadIdx.x;
    int g   = tid & 7;

    if (tid == 0) { nslots = 0; nint = 0; slotrow[0] = 0; }
    // kernel weights (stride-9 rows) + zero dummy row k=27
    if (tid < (KVOL + 1) * GROUPS) {
        int kr = tid >> 3;
        kw[kr * FSTRIDE + g] = (kr < KVOL) ? kernel4[kr * GROUPS + g]
                                           : make_float4(0.f, 0.f, 0.f, 0.f);
    }
    if (tid < GROUPS) feat[tid] = make_float4(0.f, 0.f, 0.f, 0.f); // slot 0

    // XCD slab swizzle (perf-only)
    int b = blockIdx.x;
    const int per = NREGIONS >> 3;             // 1000
    int r = (b & 7) * per + (b >> 3);

    int bx = r / (NRGN * NRGN);
    int by = (r / NRGN) % NRGN;
    int bz = r % NRGN;
    int ox = bx * RGN, oy = by * RGN, oz = bz * RGN;

    // Load 7x7x7 brick of the dense map (L2-hot, 4.25 MB total map).
    for (int i = tid; i < BVOL; i += 256) {
        int lx = i / (BSIDE * BSIDE), ly = (i / BSIDE) % BSIDE, lz = i % BSIDE;
        bs[i] = dense[((size_t)(ox + lx) * LP + (oy + ly)) * LP + (oz + lz)];
    }
    __syncthreads();

    // Slot assignment for ALL occupied brick cells + interior work queue.
    // Each thread reads/writes only its own cells -> no intra-phase hazard.
    for (int i = tid; i < BVOL; i += 256) {
        int v = bs[i];
        int s = 0;
        if (v > 0) {
            s = 1 + atomicAdd(&nslots, 1);
            slotrow[s] = v - 1;
            int lx = i / 49, ly = (i / 7) % 7, lz = i % 7;
            if ((unsigned)(lx - 1) < RGN && (unsigned)(ly - 1) < RGN &&
                (unsigned)(lz - 1) < RGN) {
                int q = atomicAdd(&nint, 1);
                cellq[q] = i;
            }
        }
        bs[i] = s;
    }
    __syncthreads();

    int ns = nslots;
    int n  = nint;
    bool ovf = (ns > FEAT_CAP);                // ~7.5 sigma: essentially never

    if (tid < 64) {
        // wave 0: build padded tap lists (needs completed slot map)
        for (int q = tid; q < n; q += 64) {
            int bidx = cellq[q];
            unsigned short* tl = &list[q * LSTR];
            int j = 0;
            #pragma unroll
            for (int k = 0; k < KVOL; ++k) {   // offsets fold to constants
                int dx = k / 9 - 1, dy = (k / 3) % 3 - 1, dz = k % 3 - 1;
                int s = bs[bidx + dx * (BSIDE * BSIDE) + dy * BSIDE + dz];
                if (s) tl[j++] = (unsigned short)((s << 5) | k);
            }
            while (j & 3) tl[j++] = (unsigned short)KVOL; // slot0, k=27: zero
            cellq[q] = bidx | (j << 10);
        }
    } else {
        // waves 1..3: stage feature rows (coalesced 128B per slot)
        int t   = tid - 64;
        int lim = ovf ? FEAT_CAP : ns;
        for (int s = 1 + (t >> 3); s <= lim; s += 24)
            feat[s * FSTRIDE + g] = in_feats4[slotrow[s] * GROUPS + g];
    }
    __syncthreads();

    int lr = tid >> 3;       // row slot 0..31
    if (!ovf) {
        for (int base = 0; base < n; base += 32) {
            int q = base + lr;
            if (q < n) {
                int cq   = cellq[q];
                int bidx = cq & 1023;
                int cr   = cq >> 10;
                int orow = slotrow[bs[bidx]];
                const uint2* tl2 = (const uint2*)&list[q * LSTR];
                float4 acc = make_float4(0.f, 0.f, 0.f, 0.f);
                for (int j = 0; j < cr; j += 4) {
                    uint2 L = tl2[j >> 2];     // 4 packed taps, octet-broadcast
                    int e0 = L.x & 0xffff, e1 = L.x >> 16;
                    int e2 = L.y & 0xffff, e3 = L.y >> 16;
                    float4 f0 = feat[(e0 >> 5) * FSTRIDE + g];
                    float4 w0 = kw[(e0 & 31) * FSTRIDE + g];
                    float4 f1 = feat[(e1 >> 5) * FSTRIDE + g];
                    float4 w1 = kw[(e1 & 31) * FSTRIDE + g];
                    float4 f2 = feat[(e2 >> 5) * FSTRIDE + g];
                    float4 w2 = kw[(e2 & 31) * FSTRIDE + g];
                    float4 f3 = feat[(e3 >> 5) * FSTRIDE + g];
                    float4 w3 = kw[(e3 & 31) * FSTRIDE + g];
                    acc.x += f0.x * w0.x; acc.y += f0.y * w0.y;
                    acc.z += f0.z * w0.z; acc.w += f0.w * w0.w;
                    acc.x += f1.x * w1.x; acc.y += f1.y * w1.y;
                    acc.z += f1.z * w1.z; acc.w += f1.w * w1.w;
                    acc.x += f2.x * w2.x; acc.y += f2.y * w2.y;
                    acc.z += f2.z * w2.z; acc.w += f2.w * w2.w;
                    acc.x += f3.x * w3.x; acc.y += f3.y * w3.y;
                    acc.z += f3.z * w3.z; acc.w += f3.w * w3.w;
                }
                out4[(size_t)orow * GROUPS + g] = acc;
            }
        }
    } else {
        // Rare overflow fallback: feats straight from global via slotrow.
        for (int base = 0; base < n; base += 32) {
            int q = base + lr;
            if (q < n) {
                int cq   = cellq[q];
                int bidx = cq & 1023;
                int cr   = cq >> 10;
                int orow = slotrow[bs[bidx]];
                const uint2* tl2 = (const uint2*)&list[q * LSTR];
                float4 acc = make_float4(0.f, 0.f, 0.f, 0.f);
                for (int j = 0; j < cr; j += 4) {
                    uint2 L = tl2[j >> 2];
                    int ee[4] = { (int)(L.x & 0xffff), (int)(L.x >> 16),
                                  (int)(L.y & 0xffff), (int)(L.y >> 16) };
                    #pragma unroll
                    for (int t = 0; t < 4; ++t) {
                        int e = ee[t];
                        float4 f = in_feats4[(size_t)slotrow[e >> 5] * GROUPS + g];
                        float4 w = kw[(e & 31) * FSTRIDE + g];
                        acc.x += f.x * w.x; acc.y += f.y * w.y;
                        acc.z += f.z * w.z; acc.w += f.w * w.w;
                    }
                }
                out4[(size_t)orow * GROUPS + g] = acc;
            }
        }
    }
}

// ---- Fallback (R1 atomic scatter) if ws is too small ------------------------
__global__ void mink_conv_scatter(const int* __restrict__ coords,
                                  const int* __restrict__ in_idx,
                                  const int* __restrict__ out_idx,
                                  const float4* __restrict__ in_feats4,
                                  const float4* __restrict__ kernel4,
                                  float* __restrict__ out,
                                  int E) {
    __shared__ float4 kws[KVOL * GROUPS];
    for (int i = threadIdx.x; i < KVOL * GROUPS; i += blockDim.x)
        kws[i] = kernel4[i];
    __syncthreads();
    int t = blockIdx.x * blockDim.x + threadIdx.x;
    if (t >= E * GROUPS) return;
    int e = t >> 3, g = t & 7;
    int vi = in_idx[e], vo = out_idx[e];
    int c0 = coords[vi * 3 + 0] - coords[vo * 3 + 0] + 1;
    int c1 = coords[vi * 3 + 1] - coords[vo * 3 + 1] + 1;
    int c2 = coords[vi * 3 + 2] - coords[vo * 3 + 2] + 1;
    int k1d = (c0 * 3 + c1) * 3 + c2;
    float4 f = in_feats4[vi * GROUPS + g];
    float4 w = kws[k1d * GROUPS + g];
    float* o = out + vo * NCH + g * 4;
    atomicAdd(o + 0, f.x * w.x);
    atomicAdd(o + 1, f.y * w.y);
    atomicAdd(o + 2, f.z * w.z);
    atomicAdd(o + 3, f.w * w.w);
}

extern "C" void kernel_launch(void* const* d_in, const int* in_sizes, int n_in,
                              void* d_out, int out_size, void* d_ws, size_t ws_size,
                              hipStream_t stream) {
    const int*   coords   = (const int*)d_in[0];
    const int*   in_idx   = (const int*)d_in[1];
    const int*   out_idx  = (const int*)d_in[2];
    const float* in_feats = (const float*)d_in[3];
    const float* kernel   = (const float*)d_in[4];

    const int E     = in_sizes[1];
    const int Nrows = out_size / NCH;

    const size_t dense_bytes = (size_t)LP * LP * LP * sizeof(int); // 4.25 MB

    if (ws_size >= dense_bytes) {
        int* dense = (int*)d_ws;
        hipMemsetAsync(dense, 0, dense_bytes, stream);

        int block = 256;
        int grid1 = (Nrows + block - 1) / block;
        build_dense<<<grid1, block, 0, stream>>>(coords, dense, Nrows);

        gather_conv_region<<<NREGIONS, 256, 0, stream>>>(
            dense, (const float4*)in_feats, (const float4*)kernel,
            (float4*)d_out);
    } else {
        hipMemsetAsync(d_out, 0, (size_t)out_size * sizeof(float), stream);
        int total = E * GROUPS;
        int block = 256;
        int grid  = (total + block - 1) / block;
        mink_conv_scatter<<<grid, block, 0, stream>>>(
            coords, in_idx, out_idx,
            (const float4*)in_feats, (const float4*)kernel,
            (float*)d_out, E);
    }
}

// Round 2
// 139.016 us; speedup vs baseline: 1.1093x; 1.1093x over previous
//
#include <hip/hip_runtime.h>

#define NCH 32          // channels
#define GROUPS 8        // float4 groups per row (32 / 4)
#define KVOL 27         // 3^3 kernel offsets
#define LG 100          // grid side
#define LP 102          // padded side (1-cell zero ring)
#define RGN 5           // region side per block
#define NRGN 20         // LG / RGN
#define NREGIONS (NRGN * NRGN * NRGN)   // 8000
#define BSIDE 7         // RGN + 2
#define BVOL 343        // brick cells
#define CELLS 125       // RGN^3
#define FSTR 9          // kw float4 stride (rotates bank starts vs 8)
#define LSTR 28         // ushort taps per row slot (56B, b64-aligned)

// ---- Kernel 1: padded dense presence map: dense[flatp] = row+1 --------------
__global__ void build_dense(const int* __restrict__ coords,
                            int* __restrict__ dense, int N) {
    int i = blockIdx.x * blockDim.x + threadIdx.x;
    if (i >= N) return;
    int x = coords[3 * i + 0];
    int y = coords[3 * i + 1];
    int z = coords[3 * i + 2];
    dense[((size_t)(x + 1) * LP + (y + 1)) * LP + (z + 1)] = i + 1;
}

// ---- Kernel 2: region gather, occupancy-first structure ---------------------
// LDS ~15KB -> 8 blocks/CU (32 waves, HW cap). Tap lists are ushort
// (slot<<5|k) with slot->row indirection; rows counting-sorted by tap count
// so each wave's 8 octets run near-equal trip counts.
__global__ __launch_bounds__(256) void gather_conv_region(
        const int* __restrict__ dense,
        const float4* __restrict__ in_feats4,
        const float4* __restrict__ kernel4,
        float4* __restrict__ out4) {
    __shared__ float4 kw[(KVOL + 1) * FSTR];        // 4032 B (row 27 = zeros)
    __shared__ int brick[BVOL];                     // slot+1 (0 = empty)
    __shared__ int slotrow[BVOL];                   // slot -> global feat row
    __shared__ int qcell[CELLS];                    // p -> (slot<<16)|cell
    __shared__ int fillA[CELLS];                    // fill cnt, then packed
    __shared__ int smap[CELLS];                     // sorted pos -> (p<<8)|cr
    __shared__ int hist[7];
    __shared__ __align__(8) unsigned short list[CELLS * LSTR]; // 7000 B
    __shared__ int nslots, nint;

    int tid = threadIdx.x;
    int g   = tid & 7;

    if (tid == 0) { nslots = 0; nint = 0; }
    if (tid < 7) hist[tid] = 0;
    if (tid < CELLS) fillA[tid] = 0;
    if (tid < (KVOL + 1) * GROUPS) {
        int kr = tid >> 3;
        kw[kr * FSTR + g] = (kr < KVOL) ? kernel4[kr * GROUPS + g]
                                        : make_float4(0.f, 0.f, 0.f, 0.f);
    }

    // XCD slab swizzle (8000 % 8 == 0 -> bijective)
    int b = blockIdx.x;
    int r = (b & 7) * (NREGIONS >> 3) + (b >> 3);
    int bx = r / (NRGN * NRGN);
    int by = (r / NRGN) % NRGN;
    int bz = r % NRGN;
    int ox = bx * RGN, oy = by * RGN, oz = bz * RGN;

    // Fused: brick load + slot assignment + interior queue (same thread owns
    // each cell across the fused steps -> no intra-phase hazard).
    for (int i = tid; i < BVOL; i += 256) {
        int lx = i / (BSIDE * BSIDE), ly = (i / BSIDE) % BSIDE, lz = i % BSIDE;
        int v = dense[((size_t)(ox + lx) * LP + (oy + ly)) * LP + (oz + lz)];
        int s = 0;
        if (v > 0) {
            s = atomicAdd(&nslots, 1);
            slotrow[s] = v - 1;
            if ((unsigned)(lx - 1) < RGN && (unsigned)(ly - 1) < RGN &&
                (unsigned)(lz - 1) < RGN) {
                int p = atomicAdd(&nint, 1);
                qcell[p] = (s << 16) | i;
            }
            s += 1;
        }
        brick[i] = s;
    }
    __syncthreads();

    int n = nint;

    // Tap-parallel list fill: (cell,k) pairs spread over all 256 lanes.
    for (int idx = tid; idx < n * KVOL; idx += 256) {
        int p = idx / KVOL;                 // const divisor -> magic mul
        int k = idx - p * KVOL;
        int cell = qcell[p] & 0xffff;
        int dx = k / 9 - 1, dy = (k / 3) % 3 - 1, dz = k % 3 - 1;
        int nb = brick[cell + dx * (BSIDE * BSIDE) + dy * BSIDE + dz];
        if (nb) {
            int pos = atomicAdd(&fillA[p], 1);
            list[p * LSTR + pos] = (unsigned short)(((nb - 1) << 5) | k);
        }
    }
    __syncthreads();

    // Pad each list to a multiple of 4 (k=27 -> zero weight, own row) and
    // histogram the padded counts (7 bins: 4,8,...,28). n<=125 -> <=2 waves.
    if (tid < n) {
        int j = fillA[tid];
        int s = qcell[tid] >> 16;
        unsigned short dummy = (unsigned short)((s << 5) | KVOL);
        while (j & 3) list[tid * LSTR + (j++)] = dummy;
        int bin = (j >> 2) - 1;             // 0..6 (j>=4: center tap always)
        int h = atomicAdd(&hist[bin], 1);
        fillA[tid] = j | (bin << 8) | (h << 16);
    }
    __syncthreads();

    // Placement: descending tap count -> each wave's 8 rows near-equal length.
    if (tid < n) {
        int f = fillA[tid];
        int j = f & 255, bin = (f >> 8) & 255, h = f >> 16;
        int pos = h;
        for (int bb = bin + 1; bb < 7; ++bb) pos += hist[bb];
        smap[pos] = (tid << 8) | j;
    }
    __syncthreads();

    // Gather: octet per row, 4 taps per step, quad list reads (b64 broadcast).
    int lr = tid >> 3;
    for (int base = 0; base < n; base += 32) {
        int lo = base + lr;
        if (lo < n) {
            int d  = smap[lo];
            int p  = d >> 8;
            int nq = (d & 255) >> 2;
            int orow = slotrow[qcell[p] >> 16];
            const uint2* tl2 = (const uint2*)&list[p * LSTR];
            float4 acc = make_float4(0.f, 0.f, 0.f, 0.f);
            for (int jq = 0; jq < nq; ++jq) {
                uint2 L = tl2[jq];
                int e0 = L.x & 0xffff, e1 = L.x >> 16;
                int e2 = L.y & 0xffff, e3 = L.y >> 16;
                int r0 = slotrow[e0 >> 5], r1 = slotrow[e1 >> 5];
                int r2 = slotrow[e2 >> 5], r3 = slotrow[e3 >> 5];
                float4 f0 = in_feats4[(size_t)r0 * GROUPS + g];
                float4 f1 = in_feats4[(size_t)r1 * GROUPS + g];
                float4 f2 = in_feats4[(size_t)r2 * GROUPS + g];
                float4 f3 = in_feats4[(size_t)r3 * GROUPS + g];
                float4 w0 = kw[(e0 & 31) * FSTR + g];
                float4 w1 = kw[(e1 & 31) * FSTR + g];
                float4 w2 = kw[(e2 & 31) * FSTR + g];
                float4 w3 = kw[(e3 & 31) * FSTR + g];
                acc.x += f0.x * w0.x; acc.y += f0.y * w0.y;
                acc.z += f0.z * w0.z; acc.w += f0.w * w0.w;
                acc.x += f1.x * w1.x; acc.y += f1.y * w1.y;
                acc.z += f1.z * w1.z; acc.w += f1.w * w1.w;
                acc.x += f2.x * w2.x; acc.y += f2.y * w2.y;
                acc.z += f2.z * w2.z; acc.w += f2.w * w2.w;
                acc.x += f3.x * w3.x; acc.y += f3.y * w3.y;
                acc.z += f3.z * w3.z; acc.w += f3.w * w3.w;
            }
            out4[(size_t)orow * GROUPS + g] = acc;
        }
    }
}

// ---- Fallback (R1 atomic scatter) if ws is too small ------------------------
__global__ void mink_conv_scatter(const int* __restrict__ coords,
                                  const int* __restrict__ in_idx,
                                  const int* __restrict__ out_idx,
                                  const float4* __restrict__ in_feats4,
                                  const float4* __restrict__ kernel4,
                                  float* __restrict__ out,
                                  int E) {
    __shared__ float4 kws[KVOL * GROUPS];
    for (int i = threadIdx.x; i < KVOL * GROUPS; i += blockDim.x)
        kws[i] = kernel4[i];
    __syncthreads();
    int t = blockIdx.x * blockDim.x + threadIdx.x;
    if (t >= E * GROUPS) return;
    int e = t >> 3, g = t & 7;
    int vi = in_idx[e], vo = out_idx[e];
    int c0 = coords[vi * 3 + 0] - coords[vo * 3 + 0] + 1;
    int c1 = coords[vi * 3 + 1] - coords[vo * 3 + 1] + 1;
    int c2 = coords[vi * 3 + 2] - coords[vo * 3 + 2] + 1;
    int k1d = (c0 * 3 + c1) * 3 + c2;
    float4 f = in_feats4[vi * GROUPS + g];
    float4 w = kws[k1d * GROUPS + g];
    float* o = out + vo * NCH + g * 4;
    atomicAdd(o + 0, f.x * w.x);
    atomicAdd(o + 1, f.y * w.y);
    atomicAdd(o + 2, f.z * w.z);
    atomicAdd(o + 3, f.w * w.w);
}

extern "C" void kernel_launch(void* const* d_in, const int* in_sizes, int n_in,
                              void* d_out, int out_size, void* d_ws, size_t ws_size,
                              hipStream_t stream) {
    const int*   coords   = (const int*)d_in[0];
    const int*   in_idx   = (const int*)d_in[1];
    const int*   out_idx  = (const int*)d_in[2];
    const float* in_feats = (const float*)d_in[3];
    const float* kernel   = (const float*)d_in[4];

    const int E     = in_sizes[1];
    const int Nrows = out_size / NCH;

    const size_t dense_bytes = (size_t)LP * LP * LP * sizeof(int); // 4.25 MB

    if (ws_size >= dense_bytes) {
        int* dense = (int*)d_ws;
        hipMemsetAsync(dense, 0, dense_bytes, stream);

        int block = 256;
        int grid1 = (Nrows + block - 1) / block;
        build_dense<<<grid1, block, 0, stream>>>(coords, dense, Nrows);

        gather_conv_region<<<NREGIONS, 256, 0, stream>>>(
            dense, (const float4*)in_feats, (const float4*)kernel,
            (float4*)d_out);
    } else {
        hipMemsetAsync(d_out, 0, (size_t)out_size * sizeof(float), stream);
        int total = E * GROUPS;
        int block = 256;
        int grid  = (total + block - 1) / block;
        mink_conv_scatter<<<grid, block, 0, stream>>>(
            coords, in_idx, out_idx,
            (const float4*)in_feats, (const float4*)kernel,
            (float*)d_out, E);
    }
}